// Round 5
// baseline (30470.554 us; speedup 1.0000x reference)
//
#include <hip/hip_runtime.h>
#include <math.h>

// ---------------------------------------------------------------------------
// QSDA block, Round 5.
// KEY FIX: output buffer is FLOAT32 (reference's output dtype). Inputs are
// bf16 (detected at runtime from n1g's bit pattern; fp32 handled too).
// Intermediates bf16: attn_v/h1 live in d_out's upper 32MB (X2); final LN2
// writes fp32 over the full 64MB in ascending chunks (overlap-safe; h1 chunk
// is copied to ws before LN2 so no intra-kernel clobber race).
// ---------------------------------------------------------------------------

#define B_ 4
#define N_ 4096
#define D_ 1024
#define DH_ 256
#define S_ 256
#define HID_ 32
#define M_ (B_ * N_)    // 16384

typedef unsigned short u16;

__device__ __forceinline__ float b2f(u16 u) {
    return __uint_as_float(((unsigned)u) << 16);
}
__device__ __forceinline__ u16 f2b(float f) {
    unsigned u = __float_as_uint(f);
    return (u16)((u + 0x7FFFu + ((u >> 16) & 1u)) >> 16);   // RNE
}
__device__ __forceinline__ float gelu_exact(float x) {
    return 0.5f * x * (1.0f + erff(x * 0.70710678118654752440f));
}
__device__ __forceinline__ float ldf(const void* p, size_t i, bool bf) {
    return bf ? b2f(((const u16*)p)[i]) : ((const float*)p)[i];
}
__device__ __forceinline__ bool detect_bf(const void* n1g) {
    // n1g is all-ones: bf16 pair -> 0x3F803F80, fp32 -> 0x3F800000
    return *(const unsigned*)n1g == 0x3F803F80u;
}

// --------------------------- zero ------------------------------------------
__global__ void zero_kernel(float* __restrict__ p, int n) {
    int i = blockIdx.x * 256 + threadIdx.x;
    if (i < n) p[i] = 0.f;
}

// --------------------------- ctx partial sums ------------------------------
__global__ __launch_bounds__(256)
void ctx_sum_kernel(const void* __restrict__ h, float* __restrict__ ctx,
                    const void* __restrict__ n1g) {
    const bool bf = detect_bf(n1g);
    const int chunks = N_ / 128;
    const int b = blockIdx.x / chunks;
    const int ch = blockIdx.x % chunks;
    const int tid = threadIdx.x;
    const size_t base = ((size_t)b * N_ + (size_t)ch * 128) * D_;
    float a[4] = {0.f, 0.f, 0.f, 0.f};
    for (int r = 0; r < 128; ++r)
#pragma unroll
        for (int q = 0; q < 4; ++q)
            a[q] += ldf(h, base + (size_t)r * D_ + q * 256 + tid, bf);
#pragma unroll
    for (int q = 0; q < 4; ++q)
        atomicAdd(&ctx[b * D_ + q * 256 + tid], a[q]);
}

// --------------------------- gamma gate ------------------------------------
__global__ __launch_bounds__(128)
void gamma_gate_kernel(const float* __restrict__ ctx,
                       const void* __restrict__ w1, const void* __restrict__ b1,
                       const void* __restrict__ g, const void* __restrict__ beta,
                       const void* __restrict__ w2, const void* __restrict__ b2,
                       float* __restrict__ out, const void* __restrict__ n1g) {
    const bool bf = detect_bf(n1g);
    const int row = blockIdx.x;
    const int tid = threadIdx.x;
    const int col = tid & 31;
    const int chunk = tid >> 5;          // 0..3
    const float xscale = 1.f / (float)N_;

    float acc = 0.f;
    for (int k = chunk * 256; k < chunk * 256 + 256; ++k)
        acc += ctx[(size_t)row * D_ + k] * xscale * ldf(w1, (size_t)k * HID_ + col, bf);

    __shared__ float part[4][HID_];
    __shared__ float s[HID_];
    __shared__ float mu_s, rstd_s;
    part[chunk][col] = acc;
    __syncthreads();
    if (tid < HID_)
        s[tid] = part[0][tid] + part[1][tid] + part[2][tid] + part[3][tid]
               + ldf(b1, tid, bf);
    __syncthreads();
    if (tid == 0) {
        float m = 0.f;
        for (int i = 0; i < HID_; ++i) m += s[i];
        m /= (float)HID_;
        float var = 0.f;
        for (int i = 0; i < HID_; ++i) { float dd = s[i] - m; var += dd * dd; }
        var /= (float)HID_;
        mu_s = m;
        rstd_s = rsqrtf(var + 1e-5f);
    }
    __syncthreads();
    if (tid < HID_) {
        float v = (s[tid] - mu_s) * rstd_s * ldf(g, tid, bf) + ldf(beta, tid, bf);
        v = v / (1.f + expf(-v));
        s[tid] = v * ldf(w2, tid, bf);
    }
    __syncthreads();
    if (tid == 0) {
        float z = 0.f;
        for (int i = 0; i < HID_; ++i) z += s[i];
        z += ldf(b2, 0, bf);
        out[row] = 1.f / (1.f + expf(-z));
    }
}

// --------------------------- fused gate+encoder+attention ------------------
#define TPB 8
__global__ __launch_bounds__(256)
void enc_attn_kernel(const void* __restrict__ h,
                     const void* __restrict__ Wr, const void* __restrict__ br,
                     const void* __restrict__ Wi, const void* __restrict__ bi,
                     const void* __restrict__ uw1, const void* __restrict__ ub1,
                     const void* __restrict__ ug, const void* __restrict__ ubeta,
                     const void* __restrict__ uw2, const void* __restrict__ ub2,
                     const void* __restrict__ m_real, const void* __restrict__ m_imag,
                     const void* __restrict__ values,
                     const float* __restrict__ gamma,
                     u16* __restrict__ attn_v, const void* __restrict__ n1g) {
    const bool bf = detect_bf(n1g);
    const int token0 = blockIdx.x * TPB;
    const int tid = threadIdx.x;

    __shared__ float sH[TPB][D_];                    // 32 KB
    __shared__ float sPr[TPB][DH_], sPi[TPB][DH_];   // 16 KB
    __shared__ float sAttn[TPB][S_];                 // 8 KB
    __shared__ float sMn[S_];                        // 1 KB
    __shared__ float sP[TPB];
    __shared__ float sInv2[TPB];
    __shared__ float sgpart[8][HID_];                // 1 KB
    __shared__ float sY[HID_];
    __shared__ float red[TPB][4];
    __shared__ float s_mu, s_rstd;

#pragma unroll
    for (int tt = 0; tt < TPB; ++tt)
        for (int j = tid; j < D_; j += 256)
            sH[tt][j] = ldf(h, (size_t)(token0 + tt) * D_ + j, bf);
    __syncthreads();

    // slot norms: thread owns slot s = tid
    {
        float msum = 0.f;
        for (int d = 0; d < DH_; ++d) {
            float mr = ldf(m_real, (size_t)tid * DH_ + d, bf);
            float mi = ldf(m_imag, (size_t)tid * DH_ + d, bf);
            msum += mr * mr + mi * mi;
        }
        sMn[tid] = 1.f / fmaxf(sqrtf(msum), 1e-12f);
    }

    // uncertainty gate per token: p_init = 0.95*sigmoid(...)
    const int col = tid & 31;
    const int kc = tid >> 5;             // 0..7
    for (int tt = 0; tt < TPB; ++tt) {
        float acc = 0.f;
        for (int k = kc * 128; k < kc * 128 + 128; ++k)
            acc += sH[tt][k] * ldf(uw1, (size_t)k * HID_ + col, bf);
        sgpart[kc][col] = acc;
        __syncthreads();
        if (tid < HID_) {
            float y = ldf(ub1, tid, bf);
#pragma unroll
            for (int q = 0; q < 8; ++q) y += sgpart[q][tid];
            sY[tid] = y;
        }
        __syncthreads();
        if (tid == 0) {
            float m = 0.f;
            for (int i = 0; i < HID_; ++i) m += sY[i];
            m /= (float)HID_;
            float var = 0.f;
            for (int i = 0; i < HID_; ++i) { float dd = sY[i] - m; var += dd * dd; }
            var /= (float)HID_;
            s_mu = m;
            s_rstd = rsqrtf(var + 1e-5f);
        }
        __syncthreads();
        if (tid < HID_) {
            float v = (sY[tid] - s_mu) * s_rstd * ldf(ug, tid, bf) + ldf(ubeta, tid, bf);
            v = v / (1.f + expf(-v));    // SiLU
            sY[tid] = v * ldf(uw2, tid, bf);
        }
        __syncthreads();
        if (tid == 0) {
            float z = ldf(ub2, 0, bf);
            for (int i = 0; i < HID_; ++i) z += sY[i];
            sP[tt] = 0.95f / (1.f + expf(-z));
        }
        __syncthreads();
    }

    // encoder: thread owns output dim d = tid (dH = 256)
    {
        const int d = tid;
        float aR[TPB], aI[TPB];
        const float b0 = ldf(br, d, bf), b1v = ldf(bi, d, bf);
#pragma unroll
        for (int tt = 0; tt < TPB; ++tt) { aR[tt] = b0; aI[tt] = b1v; }
        for (int k = 0; k < D_; ++k) {
            float wr = ldf(Wr, (size_t)k * DH_ + d, bf);
            float wi = ldf(Wi, (size_t)k * DH_ + d, bf);
#pragma unroll
            for (int tt = 0; tt < TPB; ++tt) {
                aR[tt] += sH[tt][k] * wr;
                aI[tt] += sH[tt][k] * wi;
            }
        }
#pragma unroll
        for (int tt = 0; tt < TPB; ++tt) { sPr[tt][d] = aR[tt]; sPi[tt][d] = aI[tt]; }
    }
    __syncthreads();

    // psi |.|^2 per token
#pragma unroll
    for (int tt = 0; tt < TPB; ++tt) {
        float v = sPr[tt][tid] * sPr[tt][tid] + sPi[tt][tid] * sPi[tt][tid];
#pragma unroll
        for (int off = 32; off; off >>= 1) v += __shfl_down(v, off, 64);
        if ((tid & 63) == 0) red[tt][tid >> 6] = v;
    }
    __syncthreads();
    if (tid < TPB) {
        float t = red[tid][0] + red[tid][1] + red[tid][2] + red[tid][3];
        float nrm = fmaxf(sqrtf(t), 1e-12f);
        sInv2[tid] = 1.f / (nrm * nrm);
    }
    __syncthreads();

    // overlaps: thread owns slot s = tid
    {
        float re[TPB] = {}, im[TPB] = {};
        for (int d = 0; d < DH_; ++d) {
            float mr = ldf(m_real, (size_t)tid * DH_ + d, bf);
            float mi = ldf(m_imag, (size_t)tid * DH_ + d, bf);
#pragma unroll
            for (int tt = 0; tt < TPB; ++tt) {
                float a = sPr[tt][d], c = sPi[tt][d];
                re[tt] += a * mr + c * mi;
                im[tt] += a * mi - c * mr;
            }
        }
        float mn2 = sMn[tid] * sMn[tid];
#pragma unroll
        for (int tt = 0; tt < TPB; ++tt) {
            float gmma = gamma[(token0 + tt) / N_];
            float p = sP[tt] * (1.f - gmma);
            float ov = (re[tt] * re[tt] + im[tt] * im[tt]) * mn2 * sInv2[tt];
            sAttn[tt][tid] = (1.f - p) * ov + p * (1.f / (float)DH_);
        }
    }
    __syncthreads();

    // denominator + normalize
#pragma unroll
    for (int tt = 0; tt < TPB; ++tt) {
        float v = sAttn[tt][tid];
#pragma unroll
        for (int off = 32; off; off >>= 1) v += __shfl_down(v, off, 64);
        if ((tid & 63) == 0) red[tt][tid >> 6] = v;
    }
    __syncthreads();
    if (tid < TPB) {
        float t = red[tid][0] + red[tid][1] + red[tid][2] + red[tid][3];
        sInv2[tid] = 1.f / (t + 1e-8f);
    }
    __syncthreads();
#pragma unroll
    for (int tt = 0; tt < TPB; ++tt) sAttn[tt][tid] *= sInv2[tt];
    __syncthreads();

    // attn @ values
#pragma unroll
    for (int dd = 0; dd < D_ / S_; ++dd) {
        const int d = dd * S_ + tid;
        float acc[TPB] = {};
        for (int s = 0; s < S_; ++s) {
            float v = ldf(values, (size_t)s * D_ + d, bf);
#pragma unroll
            for (int tt = 0; tt < TPB; ++tt) acc[tt] += sAttn[tt][s] * v;
        }
#pragma unroll
        for (int tt = 0; tt < TPB; ++tt)
            attn_v[(size_t)(token0 + tt) * D_ + d] = f2b(acc[tt]);
    }
}

// --------------------------- 64-row GEMM -----------------------------------
// out[r,c] = act(A[r,:]@W[:,c]+bias[c]); A bf16 internal; W/bias dual-dtype.
// 64 rows/block, 256 cols/block, K tiled by 128. A tile in LDS laid out
// k-major (sA[kk*72 + rr], pad 72 for alignment); per-k all threads
// broadcast-read the 64-row column as 8x uint4.
#define GBM 64
#define GBK 128
__global__ __launch_bounds__(256)
void gemm64(const u16* __restrict__ A, const void* __restrict__ W,
            const void* __restrict__ bias, u16* __restrict__ out,
            int N, int K, int act, const void* __restrict__ n1g) {
    __shared__ u16 sA[GBK * 72];          // 18 KB
    const bool bf = detect_bf(n1g);
    const int tid = threadIdx.x;
    const int c = blockIdx.x * 256 + tid;
    const int r0 = blockIdx.y * GBM;

    float acc[GBM] = {};

    for (int k0 = 0; k0 < K; k0 += GBK) {
        __syncthreads();
        for (int idx = tid; idx < GBM * GBK; idx += 256) {
            int rr = idx >> 7;            // 0..63
            int kk = idx & (GBK - 1);     // 0..127
            sA[kk * 72 + rr] = A[(size_t)(r0 + rr) * K + k0 + kk];
        }
        __syncthreads();

        for (int k = 0; k < GBK; ++k) {
            float w;
            if (bf) w = b2f(((const u16*)W)[(size_t)(k0 + k) * N + c]);
            else    w = ((const float*)W)[(size_t)(k0 + k) * N + c];
            const uint4* col = reinterpret_cast<const uint4*>(&sA[k * 72]);
#pragma unroll
            for (int g = 0; g < 8; ++g) {
                uint4 q = col[g];
                acc[g * 8 + 0] += __uint_as_float(q.x << 16) * w;
                acc[g * 8 + 1] += __uint_as_float(q.x & 0xFFFF0000u) * w;
                acc[g * 8 + 2] += __uint_as_float(q.y << 16) * w;
                acc[g * 8 + 3] += __uint_as_float(q.y & 0xFFFF0000u) * w;
                acc[g * 8 + 4] += __uint_as_float(q.z << 16) * w;
                acc[g * 8 + 5] += __uint_as_float(q.z & 0xFFFF0000u) * w;
                acc[g * 8 + 6] += __uint_as_float(q.w << 16) * w;
                acc[g * 8 + 7] += __uint_as_float(q.w & 0xFFFF0000u) * w;
            }
        }
    }

    float bv = ldf(bias, c, bf);
#pragma unroll 8
    for (int rr = 0; rr < GBM; ++rr) {
        float v = acc[rr] + bv;
        if (act) v = gelu_exact(v);
        out[(size_t)(r0 + rr) * N + c] = f2b(v);
    }
}

// --------------------------- row copy (bf16) -------------------------------
__global__ __launch_bounds__(256)
void copy_rows_kernel(const u16* __restrict__ src, u16* __restrict__ dst) {
    const int row = blockIdx.x;
    const int tid = threadIdx.x;
#pragma unroll
    for (int q = 0; q < 4; ++q)
        dst[(size_t)row * D_ + q * 256 + tid] = src[(size_t)row * D_ + q * 256 + tid];
}

// --------------------------- residual + LayerNorm --------------------------
// out = LN(x[xrow0+row,:] + y[row,:])*g + b. xmode: 0 = x follows detected
// input dtype, 1 = x internal bf16. Writes fp32 (outF) if given, else bf16.
__global__ __launch_bounds__(256)
void ln_add_kernel(const void* __restrict__ x, int xmode, size_t xrow0,
                   const u16* __restrict__ y,
                   const void* __restrict__ g, const void* __restrict__ b,
                   u16* __restrict__ outB, float* __restrict__ outF,
                   const void* __restrict__ n1g) {
    const bool bfin = detect_bf(n1g);
    const bool bfx = (xmode == 1) ? true : bfin;
    const int row = blockIdx.x;
    const int tid = threadIdx.x;
    __shared__ float red[4];

    float v[4];
#pragma unroll
    for (int q = 0; q < 4; ++q) {
        int d = q * 256 + tid;
        v[q] = ldf(x, (xrow0 + row) * (size_t)D_ + d, bfx)
             + b2f(y[(size_t)row * D_ + d]);
    }

    float s = v[0] + v[1] + v[2] + v[3];
#pragma unroll
    for (int off = 32; off; off >>= 1) s += __shfl_down(s, off, 64);
    if ((tid & 63) == 0) red[tid >> 6] = s;
    __syncthreads();
    float mu = (red[0] + red[1] + red[2] + red[3]) * (1.f / (float)D_);
    __syncthreads();

    float q2 = 0.f;
#pragma unroll
    for (int j = 0; j < 4; ++j) { float dd = v[j] - mu; q2 += dd * dd; }
#pragma unroll
    for (int off = 32; off; off >>= 1) q2 += __shfl_down(q2, off, 64);
    if ((tid & 63) == 0) red[tid >> 6] = q2;
    __syncthreads();
    float var = (red[0] + red[1] + red[2] + red[3]) * (1.f / (float)D_);
    float rstd = rsqrtf(var + 1e-5f);

#pragma unroll
    for (int q = 0; q < 4; ++q) {
        int d = q * 256 + tid;
        float o = (v[q] - mu) * rstd * ldf(g, d, bfin) + ldf(b, d, bfin);
        if (outF) outF[(size_t)row * D_ + d] = o;
        else      outB[(size_t)row * D_ + d] = f2b(o);
    }
}

// ---------------------------------------------------------------------------
extern "C" void kernel_launch(void* const* d_in, const int* in_sizes, int n_in,
                              void* d_out, int out_size, void* d_ws, size_t ws_size,
                              hipStream_t stream) {
    const void* h      = d_in[0];
    const void* Wr     = d_in[1];
    const void* br     = d_in[2];
    const void* Wi     = d_in[3];
    const void* bi     = d_in[4];
    const void* uw1    = d_in[5];
    const void* ub1    = d_in[6];
    const void* ug     = d_in[7];
    const void* ubeta  = d_in[8];
    const void* uw2    = d_in[9];
    const void* ub2    = d_in[10];
    const void* gw1    = d_in[11];
    const void* gb1    = d_in[12];
    const void* gg     = d_in[13];
    const void* gbeta  = d_in[14];
    const void* gw2    = d_in[15];
    const void* gb2    = d_in[16];
    const void* m_real = d_in[17];
    const void* m_imag = d_in[18];
    const void* values = d_in[19];
    const void* ow     = d_in[20];
    const void* ob     = d_in[21];
    const void* n1g    = d_in[22];
    const void* n1b    = d_in[23];
    const void* n2g    = d_in[24];
    const void* n2b    = d_in[25];
    const void* fw1    = d_in[26];
    const void* fb1    = d_in[27];
    const void* fw2    = d_in[28];
    const void* fb2    = d_in[29];

    char*  ws     = (char*)d_ws;
    float* ctx    = (float*)(ws);            // 16 KB
    float* gammap = (float*)(ws + 16384);    // 16 B
    const size_t tbase = 16640;

    // chunk rows (multiple of 64): buffers need CH*4096*2 + CH*1024*2 bytes
    int CH = 2048;
    while (CH > 64 && tbase + (size_t)CH * 10240 > ws_size) CH >>= 1;
    u16* t_buf = (u16*)(ws + tbase);             // CH x 4096 bf16 (also h1 copy)
    u16* pf    = t_buf + (size_t)CH * 4096;      // CH x 1024 bf16

    float* outF = (float*)d_out;                 // final fp32 output (64 MB)
    u16*   X2   = (u16*)d_out + (size_t)M_ * D_; // upper 32 MB: attn_v -> h1

    zero_kernel<<<16, 256, 0, stream>>>(ctx, B_ * D_);
    ctx_sum_kernel<<<B_ * (N_ / 128), 256, 0, stream>>>(h, ctx, n1g);
    gamma_gate_kernel<<<B_, 128, 0, stream>>>(ctx, gw1, gb1, gg, gbeta,
                                              gw2, gb2, gammap, n1g);

    enc_attn_kernel<<<M_ / TPB, 256, 0, stream>>>(
        h, Wr, br, Wi, bi, uw1, ub1, ug, ubeta, uw2, ub2,
        m_real, m_imag, values, gammap, X2, n1g);

    // phase 1: proj + LN1 in place over X2: h1[c] = LN(h[c] + attn_v[c]@ow+ob)
    for (int c = 0; c < M_ / CH; ++c) {
        const size_t off = (size_t)c * CH * D_;
        gemm64<<<dim3(D_ / 256, CH / GBM), 256, 0, stream>>>(
            X2 + off, ow, ob, pf, D_, D_, 0, n1g);
        ln_add_kernel<<<CH, 256, 0, stream>>>(h, 0, (size_t)c * CH, pf,
                                              n1g, n1b, X2 + off, nullptr, n1g);
    }

    // phase 2: FFN + LN2; final fp32 out written ascending (overlap-safe)
    for (int c = 0; c < M_ / CH; ++c) {
        const size_t off = (size_t)c * CH * D_;
        gemm64<<<dim3(4 * D_ / 256, CH / GBM), 256, 0, stream>>>(
            X2 + off, fw1, fb1, t_buf, 4 * D_, D_, 1, n1g);
        gemm64<<<dim3(D_ / 256, CH / GBM), 256, 0, stream>>>(
            t_buf, fw2, fb2, pf, D_, 4 * D_, 0, n1g);
        // copy h1 chunk out of X2 (t_buf is free after gemm2) so LN2's fp32
        // writes can't race its own reads in the overlapping region
        copy_rows_kernel<<<CH, 256, 0, stream>>>(X2 + off, t_buf);
        ln_add_kernel<<<CH, 256, 0, stream>>>(t_buf, 1, 0, pf,
                                              n2g, n2b, nullptr, outF + off, n1g);
    }
}

// Round 6
// 4489.631 us; speedup vs baseline: 6.7869x; 6.7869x over previous
//
#include <hip/hip_runtime.h>
#include <math.h>

// ---------------------------------------------------------------------------
// QSDA block, Round 6: MFMA GEMMs + coalesced attention.
// Inputs bf16 (runtime-detected via n1g bit pattern; fp32 fallback paths).
// Output fp32. Internal tensors bf16, fp32 accumulate.
// d_out lower 32MB = scratch (pr, pi, p_init, MrT, MiT) until phase 2
// overwrites it ascending with the final fp32 output; upper 32MB = attn_v/h1.
// ---------------------------------------------------------------------------

#define B_ 4
#define N_ 4096
#define D_ 1024
#define DH_ 256
#define S_ 256
#define HID_ 32
#define M_ (B_ * N_)    // 16384

typedef unsigned short u16;
typedef __attribute__((ext_vector_type(8))) short bfrag;   // 8 bf16 (4 VGPRs)
typedef __attribute__((ext_vector_type(4))) float ffrag;   // 4 fp32 acc

__device__ __forceinline__ float b2f(u16 u) {
    return __uint_as_float(((unsigned)u) << 16);
}
__device__ __forceinline__ u16 f2b(float f) {
    unsigned u = __float_as_uint(f);
    return (u16)((u + 0x7FFFu + ((u >> 16) & 1u)) >> 16);   // RNE
}
__device__ __forceinline__ float gelu_exact(float x) {
    return 0.5f * x * (1.0f + erff(x * 0.70710678118654752440f));
}
__device__ __forceinline__ float ldf(const void* p, size_t i, bool bf) {
    return bf ? b2f(((const u16*)p)[i]) : ((const float*)p)[i];
}
__device__ __forceinline__ bool detect_bf(const void* n1g) {
    // n1g is all-ones: bf16 pair -> 0x3F803F80, fp32 -> 0x3F800000
    return *(const unsigned*)n1g == 0x3F803F80u;
}

// --------------------------- zero ------------------------------------------
__global__ void zero_kernel(float* __restrict__ p, int n) {
    int i = blockIdx.x * 256 + threadIdx.x;
    if (i < n) p[i] = 0.f;
}

// --------------------------- ctx partial sums ------------------------------
__global__ __launch_bounds__(256)
void ctx_sum_kernel(const void* __restrict__ h, float* __restrict__ ctx,
                    const void* __restrict__ n1g) {
    const bool bf = detect_bf(n1g);
    const int chunks = N_ / 128;
    const int b = blockIdx.x / chunks;
    const int ch = blockIdx.x % chunks;
    const int tid = threadIdx.x;
    const size_t base = ((size_t)b * N_ + (size_t)ch * 128) * D_;
    float a[4] = {0.f, 0.f, 0.f, 0.f};
    for (int r = 0; r < 128; ++r)
#pragma unroll
        for (int q = 0; q < 4; ++q)
            a[q] += ldf(h, base + (size_t)r * D_ + q * 256 + tid, bf);
#pragma unroll
    for (int q = 0; q < 4; ++q)
        atomicAdd(&ctx[b * D_ + q * 256 + tid], a[q]);
}

// --------------------------- gamma gate ------------------------------------
__global__ __launch_bounds__(128)
void gamma_gate_kernel(const float* __restrict__ ctx,
                       const void* __restrict__ w1, const void* __restrict__ b1,
                       const void* __restrict__ g, const void* __restrict__ beta,
                       const void* __restrict__ w2, const void* __restrict__ b2,
                       float* __restrict__ out, const void* __restrict__ n1g) {
    const bool bf = detect_bf(n1g);
    const int row = blockIdx.x;
    const int tid = threadIdx.x;
    const int col = tid & 31;
    const int chunk = tid >> 5;
    const float xscale = 1.f / (float)N_;

    float acc = 0.f;
    for (int k = chunk * 256; k < chunk * 256 + 256; ++k)
        acc += ctx[(size_t)row * D_ + k] * xscale * ldf(w1, (size_t)k * HID_ + col, bf);

    __shared__ float part[4][HID_];
    __shared__ float s[HID_];
    __shared__ float mu_s, rstd_s;
    part[chunk][col] = acc;
    __syncthreads();
    if (tid < HID_)
        s[tid] = part[0][tid] + part[1][tid] + part[2][tid] + part[3][tid]
               + ldf(b1, tid, bf);
    __syncthreads();
    if (tid == 0) {
        float m = 0.f;
        for (int i = 0; i < HID_; ++i) m += s[i];
        m /= (float)HID_;
        float var = 0.f;
        for (int i = 0; i < HID_; ++i) { float dd = s[i] - m; var += dd * dd; }
        var /= (float)HID_;
        mu_s = m;
        rstd_s = rsqrtf(var + 1e-5f);
    }
    __syncthreads();
    if (tid < HID_) {
        float v = (s[tid] - mu_s) * rstd_s * ldf(g, tid, bf) + ldf(beta, tid, bf);
        v = v / (1.f + expf(-v));
        s[tid] = v * ldf(w2, tid, bf);
    }
    __syncthreads();
    if (tid == 0) {
        float z = 0.f;
        for (int i = 0; i < HID_; ++i) z += s[i];
        z += ldf(b2, 0, bf);
        out[row] = 1.f / (1.f + expf(-z));
    }
}

// --------------------------- uncertainty gate (per token) ------------------
// p_init[row] = 0.95 * sigmoid(silu(LN32(h[row]@uw1+ub1))@uw2+ub2)
__global__ __launch_bounds__(128)
void p_gate_kernel(const void* __restrict__ h,
                   const void* __restrict__ w1, const void* __restrict__ b1,
                   const void* __restrict__ g, const void* __restrict__ beta,
                   const void* __restrict__ w2, const void* __restrict__ b2,
                   float* __restrict__ out, const void* __restrict__ n1g) {
    const bool bf = detect_bf(n1g);
    const int row = blockIdx.x;
    const int tid = threadIdx.x;
    const int col = tid & 31;
    const int chunk = tid >> 5;

    float acc = 0.f;
    for (int k = chunk * 256; k < chunk * 256 + 256; ++k)
        acc += ldf(h, (size_t)row * D_ + k, bf) * ldf(w1, (size_t)k * HID_ + col, bf);

    __shared__ float part[4][HID_];
    __shared__ float s[HID_];
    __shared__ float mu_s, rstd_s;
    part[chunk][col] = acc;
    __syncthreads();
    if (tid < HID_)
        s[tid] = part[0][tid] + part[1][tid] + part[2][tid] + part[3][tid]
               + ldf(b1, tid, bf);
    __syncthreads();
    if (tid == 0) {
        float m = 0.f;
        for (int i = 0; i < HID_; ++i) m += s[i];
        m /= (float)HID_;
        float var = 0.f;
        for (int i = 0; i < HID_; ++i) { float dd = s[i] - m; var += dd * dd; }
        var /= (float)HID_;
        mu_s = m;
        rstd_s = rsqrtf(var + 1e-5f);
    }
    __syncthreads();
    if (tid < HID_) {
        float v = (s[tid] - mu_s) * rstd_s * ldf(g, tid, bf) + ldf(beta, tid, bf);
        v = v / (1.f + expf(-v));            // SiLU
        s[tid] = v * ldf(w2, tid, bf);
    }
    __syncthreads();
    if (tid == 0) {
        float z = 0.f;
        for (int i = 0; i < HID_; ++i) z += s[i];
        z += ldf(b2, 0, bf);
        out[row] = 0.95f / (1.f + expf(-z));
    }
}

// --------------------------- memory-slot norm (transposed out) -------------
__global__ __launch_bounds__(256)
void norm_m_kernel(const void* __restrict__ m_real, const void* __restrict__ m_imag,
                   u16* __restrict__ MrT, u16* __restrict__ MiT,
                   const void* __restrict__ n1g) {
    const bool bf = detect_bf(n1g);
    const int s = blockIdx.x;
    const int d = threadIdx.x;
    float mr = ldf(m_real, (size_t)s * DH_ + d, bf);
    float mi = ldf(m_imag, (size_t)s * DH_ + d, bf);
    float v = mr * mr + mi * mi;
#pragma unroll
    for (int off = 32; off; off >>= 1) v += __shfl_down(v, off, 64);
    __shared__ float red[4];
    if ((d & 63) == 0) red[d >> 6] = v;
    __syncthreads();
    float tot = red[0] + red[1] + red[2] + red[3];
    float inv = 1.f / fmaxf(sqrtf(tot), 1e-12f);
    MrT[d * S_ + s] = f2b(mr * inv);
    MiT[d * S_ + s] = f2b(mi * inv);
}

// --------------------------- MFMA GEMM -------------------------------------
// C[., N] = act(A@W + bias). A bf16 row-major (AEXT=1: dual-dtype external).
// W [K,N] dual-dtype. out bf16. Tile 128x128, BK=64. Requires rows%128==0,
// N%128==0, K%64==0. 256 threads = 4 waves in 2x2; each wave 64x64 via 4x4
// mfma_f32_16x16x32_bf16 fragments. LDS: A row-major, B transposed, both
// padded to stride 72 (2-way-conflict-free ds_read_b128).
template <int AEXT>
__global__ __launch_bounds__(256)
void gemm_mfma(const void* __restrict__ A, const void* __restrict__ W,
               const void* __restrict__ bias, u16* __restrict__ out,
               int N, int K, int act, const void* __restrict__ n1g) {
    const bool bf = detect_bf(n1g);
    const bool a_bf = AEXT ? bf : true;
    __shared__ short As[128 * 72];
    __shared__ short Bs[128 * 72];
    const int tid = threadIdx.x;
    const int c0 = blockIdx.x * 128;
    const int r0 = blockIdx.y * 128;
    const int lane = tid & 63, wave = tid >> 6;
    const int wm = wave & 1, wn = wave >> 1;
    const int quad = lane >> 4, l15 = lane & 15;

    ffrag acc[4][4];
#pragma unroll
    for (int i = 0; i < 4; ++i)
#pragma unroll
        for (int j = 0; j < 4; ++j)
            acc[i][j] = (ffrag){0.f, 0.f, 0.f, 0.f};

    for (int k0 = 0; k0 < K; k0 += 64) {
        __syncthreads();
        // stage A tile (128 rows x 64 k)
        if (a_bf) {
            const u16* Ab = (const u16*)A;
            for (int g = tid; g < 1024; g += 256) {
                int row = g >> 3, c8 = (g & 7) * 8;
                uint4 v = *(const uint4*)(Ab + (size_t)(r0 + row) * K + k0 + c8);
                *(uint4*)&As[row * 72 + c8] = v;
            }
        } else {
            const float* Af = (const float*)A;
            for (int g = tid; g < 1024; g += 256) {
                int row = g >> 3, c8 = (g & 7) * 8;
                const float* src = Af + (size_t)(r0 + row) * K + k0 + c8;
                union { u16 u[8]; uint4 v; } pk;
#pragma unroll
                for (int j = 0; j < 8; ++j) pk.u[j] = f2b(src[j]);
                *(uint4*)&As[row * 72 + c8] = pk.v;
            }
        }
        // stage B tile transposed (64 k x 128 n -> Bs[n][k])
        if (bf) {
            const u16* Wb = (const u16*)W;
            for (int g = tid; g < 1024; g += 256) {
                int kk = g >> 4, n8 = (g & 15) * 8;
                union { u16 u[8]; uint4 v; } pk;
                pk.v = *(const uint4*)(Wb + (size_t)(k0 + kk) * N + c0 + n8);
#pragma unroll
                for (int j = 0; j < 8; ++j) Bs[(n8 + j) * 72 + kk] = pk.u[j];
            }
        } else {
            const float* Wf = (const float*)W;
            for (int g = tid; g < 1024; g += 256) {
                int kk = g >> 4, n8 = (g & 15) * 8;
                const float* src = Wf + (size_t)(k0 + kk) * N + c0 + n8;
#pragma unroll
                for (int j = 0; j < 8; ++j) Bs[(n8 + j) * 72 + kk] = f2b(src[j]);
            }
        }
        __syncthreads();

#pragma unroll
        for (int ks = 0; ks < 2; ++ks) {
            bfrag a[4], b[4];
#pragma unroll
            for (int i = 0; i < 4; ++i)
                a[i] = *(const bfrag*)&As[(wm * 64 + i * 16 + l15) * 72 + ks * 32 + quad * 8];
#pragma unroll
            for (int j = 0; j < 4; ++j)
                b[j] = *(const bfrag*)&Bs[(wn * 64 + j * 16 + l15) * 72 + ks * 32 + quad * 8];
#pragma unroll
            for (int i = 0; i < 4; ++i)
#pragma unroll
                for (int j = 0; j < 4; ++j)
                    acc[i][j] = __builtin_amdgcn_mfma_f32_16x16x32_bf16(
                        a[i], b[j], acc[i][j], 0, 0, 0);
        }
    }

    float bv[4];
#pragma unroll
    for (int j = 0; j < 4; ++j)
        bv[j] = ldf(bias, c0 + wn * 64 + j * 16 + l15, bf);
#pragma unroll
    for (int i = 0; i < 4; ++i)
#pragma unroll
        for (int r = 0; r < 4; ++r) {
            int row_g = r0 + wm * 64 + i * 16 + quad * 4 + r;
#pragma unroll
            for (int j = 0; j < 4; ++j) {
                int col_g = c0 + wn * 64 + j * 16 + l15;
                float v = acc[i][j][r] + bv[j];
                if (act) v = gelu_exact(v);
                out[(size_t)row_g * N + col_g] = f2b(v);
            }
        }
}

// --------------------------- attention core --------------------------------
// pr/pi bf16 (unnormalized, from MFMA encoder), MrT/MiT bf16 d-major.
// TPB=8 tokens/block, 256 threads. Coalesced everywhere.
#define TPB 8
__global__ __launch_bounds__(256)
void attn_kernel(const u16* __restrict__ pr, const u16* __restrict__ pi,
                 const u16* __restrict__ MrT, const u16* __restrict__ MiT,
                 const void* __restrict__ values,
                 const float* __restrict__ p_init, const float* __restrict__ gamma,
                 u16* __restrict__ attn_v, const void* __restrict__ n1g) {
    const bool bf = detect_bf(n1g);
    const int token0 = blockIdx.x * TPB;
    const int tid = threadIdx.x;

    __shared__ float sPr[TPB][DH_], sPi[TPB][DH_];   // 16 KB
    __shared__ float sAttn[TPB][S_];                 // 8 KB
    __shared__ float sM[TPB];                        // 1/nrm^2 then 1/denom
    __shared__ float sP[TPB];
    __shared__ float red[TPB][4];

#pragma unroll
    for (int tt = 0; tt < TPB; ++tt) {
        sPr[tt][tid] = b2f(pr[(size_t)(token0 + tt) * DH_ + tid]);
        sPi[tt][tid] = b2f(pi[(size_t)(token0 + tt) * DH_ + tid]);
    }
    __syncthreads();

    // |psi|^2 per token
#pragma unroll
    for (int tt = 0; tt < TPB; ++tt) {
        float v = sPr[tt][tid] * sPr[tt][tid] + sPi[tt][tid] * sPi[tt][tid];
#pragma unroll
        for (int off = 32; off; off >>= 1) v += __shfl_down(v, off, 64);
        if ((tid & 63) == 0) red[tt][tid >> 6] = v;
    }
    __syncthreads();
    if (tid < TPB) {
        float t = red[tid][0] + red[tid][1] + red[tid][2] + red[tid][3];
        float nrm = fmaxf(sqrtf(t), 1e-12f);
        sM[tid] = 1.f / (nrm * nrm);
        int gt = token0 + tid;
        sP[tid] = p_init[gt] * (1.f - gamma[gt / N_]);
    }
    __syncthreads();

    // overlaps: thread owns slot s = tid; MrT reads coalesced across lanes
    {
        float re[TPB] = {}, im[TPB] = {};
        for (int d = 0; d < DH_; ++d) {
            float mr = b2f(MrT[d * S_ + tid]);
            float mi = b2f(MiT[d * S_ + tid]);
#pragma unroll
            for (int tt = 0; tt < TPB; ++tt) {
                float a = sPr[tt][d], c = sPi[tt][d];
                re[tt] += a * mr + c * mi;
                im[tt] += a * mi - c * mr;
            }
        }
#pragma unroll
        for (int tt = 0; tt < TPB; ++tt) {
            float p = sP[tt];
            float ov = (re[tt] * re[tt] + im[tt] * im[tt]) * sM[tt];
            sAttn[tt][tid] = (1.f - p) * ov + p * (1.f / (float)DH_);
        }
    }
    __syncthreads();

    // denominator + normalize
#pragma unroll
    for (int tt = 0; tt < TPB; ++tt) {
        float v = sAttn[tt][tid];
#pragma unroll
        for (int off = 32; off; off >>= 1) v += __shfl_down(v, off, 64);
        if ((tid & 63) == 0) red[tt][tid >> 6] = v;
    }
    __syncthreads();
    if (tid < TPB) {
        float t = red[tid][0] + red[tid][1] + red[tid][2] + red[tid][3];
        sM[tid] = 1.f / (t + 1e-8f);
    }
    __syncthreads();
#pragma unroll
    for (int tt = 0; tt < TPB; ++tt) sAttn[tt][tid] *= sM[tt];
    __syncthreads();

    // attn @ values: thread owns d = dd*256 + tid
#pragma unroll
    for (int dd = 0; dd < D_ / S_; ++dd) {
        const int d = dd * S_ + tid;
        float acc[TPB] = {};
        for (int s = 0; s < S_; ++s) {
            float v = ldf(values, (size_t)s * D_ + d, bf);
#pragma unroll
            for (int tt = 0; tt < TPB; ++tt) acc[tt] += sAttn[tt][s] * v;
        }
#pragma unroll
        for (int tt = 0; tt < TPB; ++tt)
            attn_v[(size_t)(token0 + tt) * D_ + d] = f2b(acc[tt]);
    }
}

// --------------------------- row copy (bf16) -------------------------------
__global__ __launch_bounds__(256)
void copy_rows_kernel(const u16* __restrict__ src, u16* __restrict__ dst) {
    const int row = blockIdx.x;
    const int tid = threadIdx.x;
#pragma unroll
    for (int q = 0; q < 4; ++q)
        dst[(size_t)row * D_ + q * 256 + tid] = src[(size_t)row * D_ + q * 256 + tid];
}

// --------------------------- residual + LayerNorm --------------------------
__global__ __launch_bounds__(256)
void ln_add_kernel(const void* __restrict__ x, int xmode, size_t xrow0,
                   const u16* __restrict__ y,
                   const void* __restrict__ g, const void* __restrict__ b,
                   u16* __restrict__ outB, float* __restrict__ outF,
                   const void* __restrict__ n1g) {
    const bool bfin = detect_bf(n1g);
    const bool bfx = (xmode == 1) ? true : bfin;
    const int row = blockIdx.x;
    const int tid = threadIdx.x;
    __shared__ float red[4];

    float v[4];
#pragma unroll
    for (int q = 0; q < 4; ++q) {
        int d = q * 256 + tid;
        v[q] = ldf(x, (xrow0 + row) * (size_t)D_ + d, bfx)
             + b2f(y[(size_t)row * D_ + d]);
    }

    float s = v[0] + v[1] + v[2] + v[3];
#pragma unroll
    for (int off = 32; off; off >>= 1) s += __shfl_down(s, off, 64);
    if ((tid & 63) == 0) red[tid >> 6] = s;
    __syncthreads();
    float mu = (red[0] + red[1] + red[2] + red[3]) * (1.f / (float)D_);
    __syncthreads();

    float q2 = 0.f;
#pragma unroll
    for (int j = 0; j < 4; ++j) { float dd = v[j] - mu; q2 += dd * dd; }
#pragma unroll
    for (int off = 32; off; off >>= 1) q2 += __shfl_down(q2, off, 64);
    if ((tid & 63) == 0) red[tid >> 6] = q2;
    __syncthreads();
    float var = (red[0] + red[1] + red[2] + red[3]) * (1.f / (float)D_);
    float rstd = rsqrtf(var + 1e-5f);

#pragma unroll
    for (int q = 0; q < 4; ++q) {
        int d = q * 256 + tid;
        float o = (v[q] - mu) * rstd * ldf(g, d, bfin) + ldf(b, d, bfin);
        if (outF) outF[(size_t)row * D_ + d] = o;
        else      outB[(size_t)row * D_ + d] = f2b(o);
    }
}

// ---------------------------------------------------------------------------
extern "C" void kernel_launch(void* const* d_in, const int* in_sizes, int n_in,
                              void* d_out, int out_size, void* d_ws, size_t ws_size,
                              hipStream_t stream) {
    const void* h      = d_in[0];
    const void* Wr     = d_in[1];
    const void* br     = d_in[2];
    const void* Wi     = d_in[3];
    const void* bi     = d_in[4];
    const void* uw1    = d_in[5];
    const void* ub1    = d_in[6];
    const void* ug     = d_in[7];
    const void* ubeta  = d_in[8];
    const void* uw2    = d_in[9];
    const void* ub2    = d_in[10];
    const void* gw1    = d_in[11];
    const void* gb1    = d_in[12];
    const void* gg     = d_in[13];
    const void* gbeta  = d_in[14];
    const void* gw2    = d_in[15];
    const void* gb2    = d_in[16];
    const void* m_real = d_in[17];
    const void* m_imag = d_in[18];
    const void* values = d_in[19];
    const void* ow     = d_in[20];
    const void* ob     = d_in[21];
    const void* n1g    = d_in[22];
    const void* n1b    = d_in[23];
    const void* n2g    = d_in[24];
    const void* n2b    = d_in[25];
    const void* fw1    = d_in[26];
    const void* fb1    = d_in[27];
    const void* fw2    = d_in[28];
    const void* fb2    = d_in[29];

    char*  ws     = (char*)d_ws;
    float* ctx    = (float*)(ws);            // 16 KB
    float* gammap = (float*)(ws + 16384);    // 16 B
    const size_t tbase = 16640;

    // chunk rows (multiple of 128): buffers need CH*4096*2 + CH*1024*2 bytes
    int CH = 2048;
    while (CH > 128 && tbase + (size_t)CH * 10240 > ws_size) CH >>= 1;
    u16* t_buf = (u16*)(ws + tbase);             // CH x 4096 bf16 (also h1 copy)
    u16* pf    = t_buf + (size_t)CH * 4096;      // CH x 1024 bf16

    // d_out layout: [0,32MB) scratch until phase 2 overwrites ascending
    float* outF   = (float*)d_out;
    u16*   pr     = (u16*)d_out;                                  // 8 MB
    u16*   pi     = pr + (size_t)M_ * DH_;                        // 8 MB
    float* p_init = (float*)((char*)d_out + (16u << 20));         // 64 KB
    u16*   MrT    = (u16*)((char*)d_out + (17u << 20));           // 128 KB
    u16*   MiT    = MrT + (size_t)DH_ * S_;                       // 128 KB
    u16*   X2     = (u16*)d_out + (size_t)M_ * D_;                // upper 32 MB

    zero_kernel<<<16, 256, 0, stream>>>(ctx, B_ * D_);
    ctx_sum_kernel<<<B_ * (N_ / 128), 256, 0, stream>>>(h, ctx, n1g);
    gamma_gate_kernel<<<B_, 128, 0, stream>>>(ctx, gw1, gb1, gg, gbeta,
                                              gw2, gb2, gammap, n1g);

    norm_m_kernel<<<S_, 256, 0, stream>>>(m_real, m_imag, MrT, MiT, n1g);

    // encoder projections via MFMA: pr/pi = h @ Wr/Wi + b
    gemm_mfma<1><<<dim3(DH_ / 128, M_ / 128), 256, 0, stream>>>(
        h, Wr, br, pr, DH_, D_, 0, n1g);
    gemm_mfma<1><<<dim3(DH_ / 128, M_ / 128), 256, 0, stream>>>(
        h, Wi, bi, pi, DH_, D_, 0, n1g);

    p_gate_kernel<<<M_, 128, 0, stream>>>(h, uw1, ub1, ug, ubeta,
                                          uw2, ub2, p_init, n1g);

    attn_kernel<<<M_ / TPB, 256, 0, stream>>>(pr, pi, MrT, MiT, values,
                                              p_init, gammap, X2, n1g);

    // phase 1: proj + LN1 in place over X2
    for (int c = 0; c < M_ / CH; ++c) {
        const size_t off = (size_t)c * CH * D_;
        gemm_mfma<0><<<dim3(D_ / 128, CH / 128), 256, 0, stream>>>(
            X2 + off, ow, ob, pf, D_, D_, 0, n1g);
        ln_add_kernel<<<CH, 256, 0, stream>>>(h, 0, (size_t)c * CH, pf,
                                              n1g, n1b, X2 + off, nullptr, n1g);
    }

    // phase 2: FFN + LN2; final fp32 out written ascending (overlap-safe)
    for (int c = 0; c < M_ / CH; ++c) {
        const size_t off = (size_t)c * CH * D_;
        gemm_mfma<0><<<dim3(4 * D_ / 128, CH / 128), 256, 0, stream>>>(
            X2 + off, fw1, fb1, t_buf, 4 * D_, D_, 1, n1g);
        gemm_mfma<0><<<dim3(D_ / 128, CH / 128), 256, 0, stream>>>(
            t_buf, fw2, fb2, pf, D_, 4 * D_, 0, n1g);
        copy_rows_kernel<<<CH, 256, 0, stream>>>(X2 + off, t_buf);
        ln_add_kernel<<<CH, 256, 0, stream>>>(t_buf, 1, 0, pf,
                                              n2g, n2b, nullptr, outF + off, n1g);
    }
}